// Round 18
// baseline (44.352 us; speedup 1.0000x reference)
//
#include <hip/hip_runtime.h>

#define KDIM   128
#define NELEM  8388608

typedef __attribute__((ext_vector_type(4))) float f32x4;
typedef __attribute__((ext_vector_type(2))) int   int2v;

__device__ inline f32x4 mfma8(long long a, long long b, f32x4 c) {
  return __builtin_amdgcn_mfma_f32_16x16x32_fp8_fp8(a, b, c, 0, 0, 0);
}
__device__ inline void gload16(const void* g, void* l) {
  __builtin_amdgcn_global_load_lds(
      (const __attribute__((address_space(1))) unsigned*)g,
      (__attribute__((address_space(3))) unsigned*)l, 16, 0, 0);
}
__device__ inline long long pk8(float4 v0, float4 v1) {   // 8 fp32 -> 8 fp8 e4m3 (RNE)
  int lo = __builtin_amdgcn_cvt_pk_fp8_f32(v0.x, v0.y, 0, false);
  lo     = __builtin_amdgcn_cvt_pk_fp8_f32(v0.z, v0.w, lo, true);
  int hi = __builtin_amdgcn_cvt_pk_fp8_f32(v1.x, v1.y, 0, false);
  hi     = __builtin_amdgcn_cvt_pk_fp8_f32(v1.z, v1.w, hi, true);
  int2v t; t.x = lo; t.y = hi;
  return __builtin_bit_cast(long long, t);
}
// forced single-op (score & 0xFFFFFC00) | lo5   -- v_and_or_b32
__device__ inline float and_or10(float s, int lo5, unsigned mask) {
  float r;
  asm("v_and_or_b32 %0, %1, %2, %3" : "=v"(r) : "v"(s), "s"(mask), "v"(lo5));
  return r;
}
__device__ inline float max3f(float a, float b, float c) {
  float r;
  asm("v_max3_f32 %0, %1, %2, %3" : "=v"(r) : "v"(a), "v"(b), "v"(c));
  return r;
}
__device__ inline float sumsq(float4 a, float4 b) {
  return a.x*a.x + a.y*a.y + a.z*a.z + a.w*a.w + b.x*b.x + b.y*b.y + b.z*b.z + b.w*b.w;
}
__device__ inline void merge8(float (&t)[8], int msk) {   // bitonic top-8 of 16 across lanes
  float o[8];
#pragma unroll
  for (int p = 0; p < 8; ++p) o[p] = __shfl_xor(t[p], msk);
  float m[8];
#pragma unroll
  for (int p = 0; p < 8; ++p) m[p] = fmaxf(t[p], o[7 - p]);
#pragma unroll
  for (int s = 4; s; s >>= 1)
#pragma unroll
    for (int i = 0; i < 8; ++i)
      if (!(i & s)) {
        float x = fmaxf(m[i], m[i | s]);
        m[i | s] = fminf(m[i], m[i | s]);
        m[i] = x;
      }
#pragma unroll
  for (int p = 0; p < 8; ++p) t[p] = m[p];
}
__device__ inline void ins8(float (&top)[8], float x) {   // branchless desc top-8 insert
#pragma unroll
  for (int p = 0; p < 8; ++p) {
    float mx = fmaxf(top[p], x);
    x = fminf(top[p], x);
    top[p] = mx;
  }
}

// ---- prep: emb -> fp8 (x1024, K-XOR-swizzled) + -512*||e||^2 + zero accumulators ----
__global__ void vq_prep(const float* __restrict__ emb, unsigned char* __restrict__ ebf8,
                        float* __restrict__ esqm, unsigned long long* __restrict__ lossAcc,
                        unsigned* __restrict__ cnt) {
  int j = blockIdx.x, d = threadIdx.x;
  float v = emb[j * KDIM + d];
  float vs = v * 1024.0f;
  int p = __builtin_amdgcn_cvt_pk_fp8_f32(vs, vs, 0, false);
  ebf8[j * KDIM + (d ^ ((j & 15) << 3))] = (unsigned char)(p & 0xFF);
  float s = v * v;
#pragma unroll
  for (int m = 1; m <= 32; m <<= 1) s += __shfl_xor(s, m);
  __shared__ float w[2];
  if ((d & 63) == 0) w[d >> 6] = s;
  __syncthreads();
  if (d == 0) esqm[j] = -512.0f * (w[0] + w[1]);   // score = 1024*(f.e - ||e||^2/2)
  if (j == 0 && d == 0) { lossAcc[0] = 0ULL; cnt[0] = 0u; }
}

__device__ inline void write_rows(const float* __restrict__ emb, float* __restrict__ outp,
                                  int grow0, int idx, int lane) {
#pragma unroll 4
  for (int r = 0; r < 16; ++r) {
    int s2 = __shfl(idx, r);
    float2 qv = *(const float2*)(emb + (size_t)s2 * KDIM + lane * 2);
    *(float2*)(outp + (size_t)(grow0 + r) * KDIM + lane * 2) = qv;
  }
}

// scan all 1024 codes for ONE 16-row set; pool-16 (2 groups) per top-8 insert
__device__ inline void scan_set(const unsigned char* bk0, const unsigned char* bk1,
                                const unsigned char* bk2, const unsigned char* bk3,
                                const float* esqmLds, int hi, const long long (&b)[4],
                                const int (&c8)[8], float (&top)[8]) {
  const unsigned MASK = 0xFFFFFC00u;
#pragma unroll 4
  for (int g2 = 0; g2 < 16; ++g2) {
    float xp[2];
#pragma unroll
    for (int h = 0; h < 2; ++h) {
      const int g = g2 * 2 + h;
      const int off = g * 4096;
      const float* eb = esqmLds + g * 32 + hi * 4;
      f32x4 e0 = *(const f32x4*)(eb);
      f32x4 e1 = *(const f32x4*)(eb + 16);
      long long t0 = *(const long long*)(bk0 + off);
      long long t1 = *(const long long*)(bk1 + off);
      long long t2 = *(const long long*)(bk2 + off);
      long long t3 = *(const long long*)(bk3 + off);
      long long u0 = *(const long long*)(bk0 + off + 2048);
      long long u1 = *(const long long*)(bk1 + off + 2048);
      long long u2 = *(const long long*)(bk2 + off + 2048);
      long long u3 = *(const long long*)(bk3 + off + 2048);
      f32x4 a0 = mfma8(t0, b[0], e0);
      f32x4 a1 = mfma8(u0, b[0], e1);
      a0 = mfma8(t1, b[1], a0); a1 = mfma8(u1, b[1], a1);
      a0 = mfma8(t2, b[2], a0); a1 = mfma8(u2, b[2], a1);
      a0 = mfma8(t3, b[3], a0); a1 = mfma8(u3, b[3], a1);
      float k0 = and_or10(a0[0], c8[0], MASK), k1 = and_or10(a0[1], c8[1], MASK);
      float k2 = and_or10(a0[2], c8[2], MASK), k3 = and_or10(a0[3], c8[3], MASK);
      float k4 = and_or10(a1[0], c8[4], MASK), k5 = and_or10(a1[1], c8[5], MASK);
      float k6 = and_or10(a1[2], c8[6], MASK), k7 = and_or10(a1[3], c8[7], MASK);
      float m0 = max3f(k0, k1, k2);
      float m1 = max3f(k3, k4, k5);
      float m2 = max3f(k6, k7, m0);
      float x = fmaxf(m1, m2);
      xp[h] = __builtin_bit_cast(float,
              __builtin_bit_cast(unsigned, x) | ((unsigned)g << 5));  // group bits pre-max
    }
    ins8(top, fmaxf(xp[0], xp[1]));        // pool of 16 codes (per lane) -> one insert
  }
}

// ---- main: 1 block/CU (512 thr, 8 waves); 2 sequential row-set phases,
// set0's stores drain under set1's scan ----
__global__ __launch_bounds__(512, 1) void vq_main(
    const float* __restrict__ lat, const float* __restrict__ emb,
    const int* __restrict__ ksel, const unsigned char* __restrict__ ebf8,
    const float* __restrict__ esqm, float* __restrict__ out,
    unsigned long long* __restrict__ lossAcc, unsigned* __restrict__ cnt,
    float* __restrict__ loss) {
  __shared__ __align__(16) unsigned char smem[131072 + 4096 + 64];
  float* esqmLds = (float*)(smem + 131072);
  float* wLds    = (float*)(smem + 131072 + 4096);

  const int tid = threadIdx.x, lane = tid & 63, wid = tid >> 6;   // wid 0..7
  const int n = lane & 15, hi = lane >> 4;
  const int gR0 = blockIdx.x * 256;

  // (a) row-set 0 (wid*32 + 0..15) and row-set 1 (+16) -> issue loads
  const float* rp0 = lat + (size_t)(gR0 + wid * 32 + n) * KDIM + hi * 8;
  const float* rp1 = rp0 + 16 * KDIM;
  float4 p0[4], p1[4], q0[4], q1[4];
#pragma unroll
  for (int ks = 0; ks < 4; ++ks) {
    p0[ks] = *(const float4*)(rp0 + ks * 32);
    p1[ks] = *(const float4*)(rp0 + ks * 32 + 4);
    q0[ks] = *(const float4*)(rp1 + ks * 32);
    q1[ks] = *(const float4*)(rp1 + ks * 32 + 4);
  }
  // (b) codebook (128 KB) + norms (4 KB) DMA -> LDS (pre-swizzled; linear copy)
  {
    const char* src = (const char*)ebf8 + tid * 16;
    char* dst = (char*)smem + tid * 16;
#pragma unroll
    for (int qq = 0; qq < 16; ++qq) gload16(src + qq * 8192, dst + qq * 8192);
    if (tid < 256) gload16((const char*)esqm + tid * 16, (char*)esqmLds + tid * 16);
  }
  // (c) frags (fp8) + exact ||f||^2 per set
  float fsq0, fsq1;
  long long b0[4], b1[4];
  {
    float s0 = 0.f, s1 = 0.f;
#pragma unroll
    for (int ks = 0; ks < 4; ++ks) {
      s0 += sumsq(p0[ks], p1[ks]);
      s1 += sumsq(q0[ks], q1[ks]);
    }
    s0 += __shfl_xor(s0, 16); s0 += __shfl_xor(s0, 32);
    s1 += __shfl_xor(s1, 16); s1 += __shfl_xor(s1, 32);
    fsq0 = s0; fsq1 = s1;
#pragma unroll
    for (int ks = 0; ks < 4; ++ks) {
      b0[ks] = pk8(p0[ks], p1[ks]);
      b1[ks] = pk8(q0[ks], q1[ks]);
    }
  }
  asm volatile("s_waitcnt vmcnt(0)" ::: "memory");
  __builtin_amdgcn_s_barrier();

  // A-read addressing: byte = row*128 + ((ks*32+hi*8) ^ ((row&15)<<3))
  const unsigned char* ab = smem + n * 128 + ((hi ^ (n & 3)) << 3);
  const int nh = n >> 2;
  const unsigned char* bk0 = ab + ((0 ^ nh) << 5);
  const unsigned char* bk1 = ab + ((1 ^ nh) << 5);
  const unsigned char* bk2 = ab + ((2 ^ nh) << 5);
  const unsigned char* bk3 = ab + ((3 ^ nh) << 5);

  // per-lane 5-bit index constants (u*16 + hi*4 + r), fixed across groups
  int c8[8];
#pragma unroll
  for (int r = 0; r < 4; ++r) { c8[r] = hi * 4 + r; c8[4 + r] = 16 + hi * 4 + r; }

  int kk = ksel[lane & 7];                 // row&7 == n&7 == lane&7 for both sets
  kk = kk < 0 ? 0 : (kk > 7 ? 7 : kk);

  const float NINF = __builtin_bit_cast(float, 0xFF800000u);

  // ---- phase A: set 0 scan -> merge -> pick -> write (stores drain under phase B)
  float top0[8];
#pragma unroll
  for (int p = 0; p < 8; ++p) top0[p] = NINF;
  scan_set(bk0, bk1, bk2, bk3, esqmLds, hi, b0, c8, top0);
  merge8(top0, 16); merge8(top0, 32);
  float sel0 = top0[0];
#pragma unroll
  for (int p = 1; p < 8; ++p) sel0 = (kk == p) ? top0[p] : sel0;
  unsigned sb0 = __builtin_bit_cast(unsigned, sel0);
  int idx0 = (int)(sb0 & 1023u);
  float rl0 = fsq0 - __builtin_bit_cast(float, sb0 & 0xFFFFFC00u) * (1.0f / 512.0f);
  write_rows(emb, out, gR0 + wid * 32, idx0, lane);

  // ---- phase B: set 1 scan -> merge -> pick -> write
  float top1[8];
#pragma unroll
  for (int p = 0; p < 8; ++p) top1[p] = NINF;
  scan_set(bk0, bk1, bk2, bk3, esqmLds, hi, b1, c8, top1);
  merge8(top1, 16); merge8(top1, 32);
  float sel1 = top1[0];
#pragma unroll
  for (int p = 1; p < 8; ++p) sel1 = (kk == p) ? top1[p] : sel1;
  unsigned sb1 = __builtin_bit_cast(unsigned, sel1);
  int idx1 = (int)(sb1 & 1023u);
  float rl1 = fsq1 - __builtin_bit_cast(float, sb1 & 0xFFFFFC00u) * (1.0f / 512.0f);
  write_rows(emb, out, gR0 + wid * 32 + 16, idx1, lane);

  // deterministic loss: per-block double sum -> fixed-point int64 atomic;
  // last block converts (integer adds associative -> replay-stable)
  float c = (lane < 16) ? (rl0 + rl1) : 0.f;
#pragma unroll
  for (int m = 1; m <= 32; m <<= 1) c += __shfl_xor(c, m);
  if (lane == 0) wLds[wid] = c;
  __syncthreads();
  if (tid == 0) {
    double bs = 0.0;
#pragma unroll
    for (int w = 0; w < 8; ++w) bs += (double)wLds[w];
    long long iv = (long long)(bs * 1048576.0 + 0.5);
    atomicAdd(lossAcc, (unsigned long long)iv);
    __threadfence();
    unsigned done = atomicAdd(cnt, 1u);
    if (done == 255u) {
      unsigned long long tot = atomicAdd(lossAcc, 0ULL);
      loss[0] = (float)((double)(long long)tot * (1.25 / (1048576.0 * 8388608.0)));
    }
  }
}

extern "C" void kernel_launch(void* const* d_in, const int* in_sizes, int n_in,
                              void* d_out, int out_size, void* d_ws, size_t ws_size,
                              hipStream_t stream) {
  const float* lat = (const float*)d_in[0];   // [8192,1024] fp32
  const float* emb = (const float*)d_in[1];   // [1024,128]  fp32
  const int* ksel = (const int*)d_in[2];      // [8] int32
  float* out = (float*)d_out;                 // quantized[8388608] + loss[1]

  unsigned char* ebf8 = (unsigned char*)d_ws;                 // 131072 B swizzled fp8 codes
  float* esqm = (float*)((char*)d_ws + 131072);               // 4096 B (-512*||e||^2)
  unsigned long long* lossAcc =
      (unsigned long long*)((char*)d_ws + 135168);            // 8 B fixed-point loss
  unsigned* cnt = (unsigned*)((char*)d_ws + 135176);          // 4 B block counter

  vq_prep<<<1024, 128, 0, stream>>>(emb, ebf8, esqm, lossAcc, cnt);
  vq_main<<<256, 512, 0, stream>>>(lat, emb, ksel, ebf8, esqm, out, lossAcc, cnt,
                                   out + NELEM);
}

// Round 19
// 40.655 us; speedup vs baseline: 1.0909x; 1.0909x over previous
//
#include <hip/hip_runtime.h>

#define KDIM   128
#define NELEM  8388608

typedef __attribute__((ext_vector_type(4)))  float f32x4;
typedef __attribute__((ext_vector_type(16))) float f32x16;
typedef __attribute__((ext_vector_type(2)))  int   int2v;

__device__ inline f32x16 mfma32(long long a, long long b, f32x16 c) {
  return __builtin_amdgcn_mfma_f32_32x32x16_fp8_fp8(a, b, c, 0, 0, 0);
}
__device__ inline void gload16(const void* g, void* l) {
  __builtin_amdgcn_global_load_lds(
      (const __attribute__((address_space(1))) unsigned*)g,
      (__attribute__((address_space(3))) unsigned*)l, 16, 0, 0);
}
__device__ inline long long pk8(float4 v0, float4 v1) {   // 8 fp32 -> 8 fp8 e4m3 (RNE)
  int lo = __builtin_amdgcn_cvt_pk_fp8_f32(v0.x, v0.y, 0, false);
  lo     = __builtin_amdgcn_cvt_pk_fp8_f32(v0.z, v0.w, lo, true);
  int hi = __builtin_amdgcn_cvt_pk_fp8_f32(v1.x, v1.y, 0, false);
  hi     = __builtin_amdgcn_cvt_pk_fp8_f32(v1.z, v1.w, hi, true);
  int2v t; t.x = lo; t.y = hi;
  return __builtin_bit_cast(long long, t);
}
// forced single-op (score & 0xFFFFFC00) | lo5  -- v_and_or_b32
__device__ inline float and_or10(float s, int lo5, unsigned mask) {
  float r;
  asm("v_and_or_b32 %0, %1, %2, %3" : "=v"(r) : "v"(s), "s"(mask), "v"(lo5));
  return r;
}
__device__ inline float max3f(float a, float b, float c) {
  float r;
  asm("v_max3_f32 %0, %1, %2, %3" : "=v"(r) : "v"(a), "v"(b), "v"(c));
  return r;
}
__device__ inline float sumsq(float4 a, float4 b) {
  return a.x*a.x + a.y*a.y + a.z*a.z + a.w*a.w + b.x*b.x + b.y*b.y + b.z*b.z + b.w*b.w;
}
__device__ inline void merge8(float (&t)[8], int msk) {   // bitonic top-8 of 16 across lanes
  float o[8];
#pragma unroll
  for (int p = 0; p < 8; ++p) o[p] = __shfl_xor(t[p], msk);
  float m[8];
#pragma unroll
  for (int p = 0; p < 8; ++p) m[p] = fmaxf(t[p], o[7 - p]);
#pragma unroll
  for (int s = 4; s; s >>= 1)
#pragma unroll
    for (int i = 0; i < 8; ++i)
      if (!(i & s)) {
        float x = fmaxf(m[i], m[i | s]);
        m[i | s] = fminf(m[i], m[i | s]);
        m[i] = x;
      }
#pragma unroll
  for (int p = 0; p < 8; ++p) t[p] = m[p];
}
__device__ inline void ins8(float (&top)[8], float x) {   // branchless desc top-8 insert
#pragma unroll
  for (int p = 0; p < 8; ++p) {
    float mx = fmaxf(top[p], x);
    x = fminf(top[p], x);
    top[p] = mx;
  }
}

// ---- prep: emb -> fp8 (x1024, byte-XOR swizzle) + -512*||e||^2 + zero accumulators ----
__global__ void vq_prep(const float* __restrict__ emb, unsigned char* __restrict__ ebf8,
                        float* __restrict__ esqm, unsigned long long* __restrict__ lossAcc,
                        unsigned* __restrict__ cnt) {
  int j = blockIdx.x, d = threadIdx.x;
  float v = emb[j * KDIM + d];
  float vs = v * 1024.0f;
  int p = __builtin_amdgcn_cvt_pk_fp8_f32(vs, vs, 0, false);
  ebf8[j * KDIM + (d ^ ((j & 15) << 3))] = (unsigned char)(p & 0xFF);
  float s = v * v;
#pragma unroll
  for (int m = 1; m <= 32; m <<= 1) s += __shfl_xor(s, m);
  __shared__ float w[2];
  if ((d & 63) == 0) w[d >> 6] = s;
  __syncthreads();
  if (d == 0) esqm[j] = -512.0f * (w[0] + w[1]);   // score = 1024*(f.e - ||e||^2/2)
  if (j == 0 && d == 0) { lossAcc[0] = 0ULL; cnt[0] = 0u; }
}

// ---- main: 1 block/CU (512 thr, 8 waves); 32x32x16 MFMA, lane-local rows ----
__global__ __launch_bounds__(512, 1) void vq_main(
    const float* __restrict__ lat, const float* __restrict__ emb,
    const int* __restrict__ ksel, const unsigned char* __restrict__ ebf8,
    const float* __restrict__ esqm, float* __restrict__ out,
    unsigned long long* __restrict__ lossAcc, unsigned* __restrict__ cnt,
    float* __restrict__ loss) {
  __shared__ __align__(16) unsigned char smem[131072 + 4096 + 64];
  float* esqmLds = (float*)(smem + 131072);
  float* wLds    = (float*)(smem + 131072 + 4096);

  const int tid = threadIdx.x, lane = tid & 63, wid = tid >> 6;   // wid 0..7
  const int r32 = lane & 31, h = lane >> 5;                       // lane row / k-half
  const int gR0 = blockIdx.x * 256;
  const int row0 = gR0 + wid * 32;

  // (a) latents: lane owns row row0+r32; 8 k-slices of 8 floats (k = i*16 + h*8)
  const float* rp = lat + (size_t)(row0 + r32) * KDIM + h * 8;
  float4 v0[8], v1[8];
#pragma unroll
  for (int i = 0; i < 8; ++i) {
    v0[i] = *(const float4*)(rp + i * 16);
    v1[i] = *(const float4*)(rp + i * 16 + 4);
  }
  // (b) codebook (128 KB) + norms (4 KB) DMA -> LDS (pre-swizzled; linear copy)
  {
    const char* src = (const char*)ebf8 + tid * 16;
    char* dst = (char*)smem + tid * 16;
#pragma unroll
    for (int qq = 0; qq < 16; ++qq) gload16(src + qq * 8192, dst + qq * 8192);
    if (tid < 256) gload16((const char*)esqm + tid * 16, (char*)esqmLds + tid * 16);
  }
  // (c) B-frags (fp8) + exact ||f||^2 (lane pair l, l+32 covers full row)
  float fsq;
  long long b[8];
  {
    float s = 0.f;
#pragma unroll
    for (int i = 0; i < 8; ++i) {
      s += sumsq(v0[i], v1[i]);
      b[i] = pk8(v0[i], v1[i]);
    }
    s += __shfl_xor(s, 32);
    fsq = s;
  }
  asm volatile("s_waitcnt vmcnt(0)" ::: "memory");
  __builtin_amdgcn_s_barrier();

  // A bases: code row (g*32 + r32), byte = row*128 + ((i*16 + h*8) ^ ((r32&15)<<3))
  const unsigned char* aBase[8];
#pragma unroll
  for (int i = 0; i < 8; ++i)
    aBase[i] = smem + r32 * 128 + ((i * 16 + h * 8) ^ ((r32 & 15) << 3));

  // per-lane code ids within a group: m(reg) = (reg&3) + 8*(reg>>2) + 4*h  (5 bits)
  int c16[16];
#pragma unroll
  for (int rg = 0; rg < 16; ++rg) c16[rg] = (rg & 3) + 8 * (rg >> 2) + 4 * h;
  const unsigned MASK = 0xFFFFFC00u;

  const float NINF = __builtin_bit_cast(float, 0xFF800000u);
  float top[8];
#pragma unroll
  for (int p = 0; p < 8; ++p) top[p] = NINF;

#pragma unroll 2
  for (int g2 = 0; g2 < 16; ++g2) {
    const int gA = g2 * 2, gB = g2 * 2 + 1;
    // acc init = -512*||e||^2 for each lane's 16 codes (broadcast b128 reads)
    f32x16 accA, accB;
#pragma unroll
    for (int q = 0; q < 4; ++q) {
      f32x4 eA = *(const f32x4*)(esqmLds + gA * 32 + h * 4 + q * 8);
      f32x4 eB = *(const f32x4*)(esqmLds + gB * 32 + h * 4 + q * 8);
#pragma unroll
      for (int e = 0; e < 4; ++e) { accA[q * 4 + e] = eA[e]; accB[q * 4 + e] = eB[e]; }
    }
    // 2 independent 8-deep K-chains (16 MFMAs, 16 ds_read_b64)
#pragma unroll
    for (int i = 0; i < 8; ++i) {
      long long aA = *(const long long*)(aBase[i] + gA * 4096);
      long long aB = *(const long long*)(aBase[i] + gB * 4096);
      accA = mfma32(aA, b[i], accA);
      accB = mfma32(aB, b[i], accB);
    }
    // select: pack 5-bit id, 16->1 max tree per group, OR group bits, pool 2 groups
    float xA, xB;
    {
      float k[16];
#pragma unroll
      for (int rg = 0; rg < 16; ++rg) k[rg] = and_or10(accA[rg], c16[rg], MASK);
      float p0 = max3f(k[0], k[1], k[2]),  p1 = max3f(k[3], k[4], k[5]);
      float p2 = max3f(k[6], k[7], k[8]),  p3 = max3f(k[9], k[10], k[11]);
      float p4 = max3f(k[12], k[13], k[14]);
      float x = fmaxf(max3f(p0, p1, k[15]), max3f(p2, p3, p4));
      xA = __builtin_bit_cast(float, __builtin_bit_cast(unsigned, x) | ((unsigned)gA << 5));
    }
    {
      float k[16];
#pragma unroll
      for (int rg = 0; rg < 16; ++rg) k[rg] = and_or10(accB[rg], c16[rg], MASK);
      float p0 = max3f(k[0], k[1], k[2]),  p1 = max3f(k[3], k[4], k[5]);
      float p2 = max3f(k[6], k[7], k[8]),  p3 = max3f(k[9], k[10], k[11]);
      float p4 = max3f(k[12], k[13], k[14]);
      float x = fmaxf(max3f(p0, p1, k[15]), max3f(p2, p3, p4));
      xB = __builtin_bit_cast(float, __builtin_bit_cast(unsigned, x) | ((unsigned)gB << 5));
    }
    ins8(top, fmaxf(xA, xB));
  }

  // combine lane pair (l, l+32) -> full per-row top-8; pick k-th
  merge8(top, 32);
  int kk = ksel[lane & 7];                 // row&7 == r32&7 == lane&7
  kk = kk < 0 ? 0 : (kk > 7 ? 7 : kk);
  float sel = top[0];
#pragma unroll
  for (int p = 1; p < 8; ++p) sel = (kk == p) ? top[p] : sel;
  unsigned sb = __builtin_bit_cast(unsigned, sel);
  int idx = (int)(sb & 1023u);
  float rl = fsq - __builtin_bit_cast(float, sb & 0xFFFFFC00u) * (1.0f / 512.0f);

  // write 32 rows (wave-cooperative, coalesced 512B bursts)
#pragma unroll 4
  for (int r = 0; r < 32; ++r) {
    int s2 = __shfl(idx, r);
    float2 qv = *(const float2*)(emb + (size_t)s2 * KDIM + lane * 2);
    *(float2*)(out + (size_t)(row0 + r) * KDIM + lane * 2) = qv;
  }

  // deterministic loss: per-block double sum -> fixed-point int64 atomic;
  // last block converts (integer adds associative -> replay-stable)
  float c = (lane < 32) ? rl : 0.f;
#pragma unroll
  for (int m = 1; m <= 32; m <<= 1) c += __shfl_xor(c, m);
  if (lane == 0) wLds[wid] = c;
  __syncthreads();
  if (tid == 0) {
    double bs = 0.0;
#pragma unroll
    for (int w = 0; w < 8; ++w) bs += (double)wLds[w];
    long long iv = (long long)(bs * 1048576.0 + 0.5);
    atomicAdd(lossAcc, (unsigned long long)iv);
    __threadfence();
    unsigned done = atomicAdd(cnt, 1u);
    if (done == 255u) {
      unsigned long long tot = atomicAdd(lossAcc, 0ULL);
      loss[0] = (float)((double)(long long)tot * (1.25 / (1048576.0 * 8388608.0)));
    }
  }
}

extern "C" void kernel_launch(void* const* d_in, const int* in_sizes, int n_in,
                              void* d_out, int out_size, void* d_ws, size_t ws_size,
                              hipStream_t stream) {
  const float* lat = (const float*)d_in[0];   // [8192,1024] fp32
  const float* emb = (const float*)d_in[1];   // [1024,128]  fp32
  const int* ksel = (const int*)d_in[2];      // [8] int32
  float* out = (float*)d_out;                 // quantized[8388608] + loss[1]

  unsigned char* ebf8 = (unsigned char*)d_ws;                 // 131072 B swizzled fp8 codes
  float* esqm = (float*)((char*)d_ws + 131072);               // 4096 B (-512*||e||^2)
  unsigned long long* lossAcc =
      (unsigned long long*)((char*)d_ws + 135168);            // 8 B fixed-point loss
  unsigned* cnt = (unsigned*)((char*)d_ws + 135176);          // 4 B block counter

  vq_prep<<<1024, 128, 0, stream>>>(emb, ebf8, esqm, lossAcc, cnt);
  vq_main<<<256, 512, 0, stream>>>(lat, emb, ksel, ebf8, esqm, out, lossAcc, cnt,
                                   out + NELEM);
}